// Round 1
// baseline (919.752 us; speedup 1.0000x reference)
//
#include <hip/hip_runtime.h>

#define NN 16384
#define EE 8192
#define KIN 256
#define FOUT 128

typedef short short8 __attribute__((ext_vector_type(8)));
typedef short short4v __attribute__((ext_vector_type(4)));
typedef float f32x4 __attribute__((ext_vector_type(4)));
typedef __bf16 bf16x8 __attribute__((ext_vector_type(8)));

// fp32 -> bf16 bits, RNE via hardware convert (pairs into v_cvt_pk_bf16_f32)
__device__ inline unsigned short f2bf(float f) {
    union { __bf16 h; unsigned short u; } v;
    v.h = (__bf16)f;
    return v.u;
}

__device__ inline f32x4 mfma_bf16(short8 a, short8 b, f32x4 c) {
    union { short8 s; bf16x8 h; } ua, ub;
    ua.s = a; ub.s = b;
    return __builtin_amdgcn_mfma_f32_16x16x32_bf16(ua.h, ub.h, c, 0, 0, 0);
}

// ---------------- K1: yT[f][n] = bf16( (x @ W)[n][f] ) ----------------
__global__ __launch_bounds__(256) void k1_xw_yT(
    const float* __restrict__ x, const float* __restrict__ w,
    unsigned short* __restrict__ yT) {
    __shared__ union {
        unsigned short wT[FOUT * KIN];   // 64 KB, [f][k] XOR-swizzled (16B chunks)
        unsigned short cT[FOUT * 72];    // epilogue transpose buffer
    } sm;
    const int t  = threadIdx.x;
    const int l  = t & 63;
    const int wv = t >> 6;
    const int q4 = l >> 4;

    {   // stage W transposed + bf16 + swizzled
        const int f  = t >> 1;
        const int kh = (t & 1) * 128;
        #pragma unroll 4
        for (int q = 0; q < 16; ++q) {
            short8 pk;
            #pragma unroll
            for (int j = 0; j < 8; ++j)
                pk[j] = (short)f2bf(w[(kh + q * 8 + j) * FOUT + f]);
            int c = ((kh >> 3) + q) ^ (f & 7);
            *(short8*)&sm.wT[f * KIN + c * 8] = pk;
        }
    }
    __syncthreads();

    const int nBase = blockIdx.x * 64;
    const int n = nBase + wv * 16 + (l & 15);
    f32x4 acc[8];
    #pragma unroll
    for (int i = 0; i < 8; ++i) acc[i] = (f32x4)0.0f;

    #pragma unroll
    for (int kk = 0; kk < 8; ++kk) {
        const float* xr = x + (size_t)n * KIN + kk * 32 + q4 * 8;
        float4 v0 = *(const float4*)xr;
        float4 v1 = *(const float4*)(xr + 4);
        short8 a;
        a[0] = (short)f2bf(v0.x); a[1] = (short)f2bf(v0.y);
        a[2] = (short)f2bf(v0.z); a[3] = (short)f2bf(v0.w);
        a[4] = (short)f2bf(v1.x); a[5] = (short)f2bf(v1.y);
        a[6] = (short)f2bf(v1.z); a[7] = (short)f2bf(v1.w);
        #pragma unroll
        for (int ft = 0; ft < 8; ++ft) {
            int f = ft * 16 + (l & 15);
            int c = (kk * 4 + q4) ^ (f & 7);
            short8 b = *(const short8*)&sm.wT[f * KIN + c * 8];
            acc[ft] = mfma_bf16(a, b, acc[ft]);
        }
    }
    __syncthreads();

    #pragma unroll
    for (int ft = 0; ft < 8; ++ft) {
        short4v pk;
        #pragma unroll
        for (int r = 0; r < 4; ++r) pk[r] = (short)f2bf(acc[ft][r]);
        int f = ft * 16 + (l & 15);
        *(short4v*)&sm.cT[f * 72 + wv * 16 + q4 * 4] = pk;
    }
    __syncthreads();
    {
        const int f  = t >> 1;
        const int nh = (t & 1) * 32;
        #pragma unroll
        for (int qq = 0; qq < 4; ++qq) {
            short8 v = *(const short8*)&sm.cT[f * 72 + nh + qq * 8];
            *(short8*)&yT[(size_t)f * NN + nBase + nh + qq * 8] = v;
        }
    }
}

// ---------------- K2: eyf[e][f] += D_v[e] * (MT @ y)[e][f] ----------------
// grid (128, 8): 4 blocks/CU. Double-buffered LDS (B) + double-buffered regs (A).
// Per chunk: barrier -> issue next A+B loads -> pure ds_read+MFMA -> commit.
__global__ __launch_bounds__(256, 4) void k2_mt_y(
    const float* __restrict__ MT, const unsigned short* __restrict__ yT,
    const float* __restrict__ dv, float* __restrict__ eyf) {
    __shared__ unsigned short blds[2][FOUT * 64];   // 2 x 16 KB, [f][k] swizzled
    const int t  = threadIdx.x;
    const int l  = t & 63;
    const int wv = t >> 6;
    const int q4 = l >> 4;
    const int eBase = blockIdx.x * 64;
    const int sBase = blockIdx.y * 2048;
    const int e = eBase + wv * 16 + (l & 15);
    const float* arow = MT + (size_t)e * NN;

    f32x4 acc[8];
    #pragma unroll
    for (int i = 0; i < 8; ++i) acc[i] = (f32x4)0.0f;

    const int sf = t >> 1;
    const int skoff = (t & 1) * 32;
    const int scb = skoff >> 3;
    const int sfx = sf & 7;
    const unsigned short* srcBase = yT + (size_t)sf * NN + skoff;

    {   // prologue: stage B chunk 0 into buf 0
        const unsigned short* src = srcBase + sBase;
        short8 v0 = *(const short8*)(src);
        short8 v1 = *(const short8*)(src + 8);
        short8 v2 = *(const short8*)(src + 16);
        short8 v3 = *(const short8*)(src + 24);
        *(short8*)&blds[0][sf * 64 + ((scb + 0) ^ sfx) * 8] = v0;
        *(short8*)&blds[0][sf * 64 + ((scb + 1) ^ sfx) * 8] = v1;
        *(short8*)&blds[0][sf * 64 + ((scb + 2) ^ sfx) * 8] = v2;
        *(short8*)&blds[0][sf * 64 + ((scb + 3) ^ sfx) * 8] = v3;
    }
    short8 aF[2];   // current-chunk A, pre-packed bf16
    {   // prologue: load + pack A chunk 0
        #pragma unroll
        for (int kk = 0; kk < 2; ++kk) {
            const float* ar = arow + sBase + kk * 32 + q4 * 8;
            float4 v0 = *(const float4*)ar;
            float4 v1 = *(const float4*)(ar + 4);
            aF[kk][0] = (short)f2bf(v0.x); aF[kk][1] = (short)f2bf(v0.y);
            aF[kk][2] = (short)f2bf(v0.z); aF[kk][3] = (short)f2bf(v0.w);
            aF[kk][4] = (short)f2bf(v1.x); aF[kk][5] = (short)f2bf(v1.y);
            aF[kk][6] = (short)f2bf(v1.z); aF[kk][7] = (short)f2bf(v1.w);
        }
    }

    for (int cc = 0; cc < 32; ++cc) {
        __syncthreads();   // buf[cc&1] staged; prior reads of buf[(cc+1)&1] done

        // issue next-chunk loads (B staging + A rows) — in flight during compute
        short8 v0, v1, v2, v3;
        float4 na0[2], na1[2];
        if (cc != 31) {
            const int kn = sBase + cc * 64 + 64;
            const unsigned short* src = srcBase + kn;
            v0 = *(const short8*)(src);
            v1 = *(const short8*)(src + 8);
            v2 = *(const short8*)(src + 16);
            v3 = *(const short8*)(src + 24);
            #pragma unroll
            for (int kk = 0; kk < 2; ++kk) {
                const float* ar = arow + kn + kk * 32 + q4 * 8;
                na0[kk] = *(const float4*)ar;
                na1[kk] = *(const float4*)(ar + 4);
            }
        }
        // compute current chunk: pure ds_read_b128 + MFMA, no global waits
        #pragma unroll
        for (int kk = 0; kk < 2; ++kk) {
            #pragma unroll
            for (int ft = 0; ft < 8; ++ft) {
                int f = ft * 16 + (l & 15);
                int c = (kk * 4 + q4) ^ (f & 7);
                short8 b = *(const short8*)&blds[cc & 1][f * 64 + c * 8];
                acc[ft] = mfma_bf16(aF[kk], b, acc[ft]);
            }
        }
        // commit next chunk: B into the other LDS buffer, A packed into regs
        if (cc != 31) {
            unsigned short* dst = &blds[(cc + 1) & 1][sf * 64];
            *(short8*)&dst[((scb + 0) ^ sfx) * 8] = v0;
            *(short8*)&dst[((scb + 1) ^ sfx) * 8] = v1;
            *(short8*)&dst[((scb + 2) ^ sfx) * 8] = v2;
            *(short8*)&dst[((scb + 3) ^ sfx) * 8] = v3;
            #pragma unroll
            for (int kk = 0; kk < 2; ++kk) {
                aF[kk][0] = (short)f2bf(na0[kk].x); aF[kk][1] = (short)f2bf(na0[kk].y);
                aF[kk][2] = (short)f2bf(na0[kk].z); aF[kk][3] = (short)f2bf(na0[kk].w);
                aF[kk][4] = (short)f2bf(na1[kk].x); aF[kk][5] = (short)f2bf(na1[kk].y);
                aF[kk][6] = (short)f2bf(na1[kk].z); aF[kk][7] = (short)f2bf(na1[kk].w);
            }
        }
    }
    // epilogue: row scaling by dv (commutes with the K-sum), then atomic accumulate
    const int eo = eBase + wv * 16 + q4 * 4;
    float dvr[4];
    #pragma unroll
    for (int r = 0; r < 4; ++r) dvr[r] = dv[eo + r];
    #pragma unroll
    for (int ft = 0; ft < 8; ++ft) {
        int f = ft * 16 + (l & 15);
        #pragma unroll
        for (int r = 0; r < 4; ++r)
            atomicAdd(&eyf[(size_t)(eo + r) * FOUT + f], dvr[r] * acc[ft][r]);
    }
}

// ---------------- K2b: eyT[f][e] = bf16(eyf[e][f]) ----------------
__global__ __launch_bounds__(256) void k2b_cvtT(
    const float* __restrict__ eyf, unsigned short* __restrict__ eyT) {
    int idx = blockIdx.x * 256 + threadIdx.x;   // 128 * 1024
    int e8 = idx & 1023;
    int f  = idx >> 10;
    short8 pk;
    #pragma unroll
    for (int j = 0; j < 8; ++j)
        pk[j] = (short)f2bf(eyf[(size_t)(e8 * 8 + j) * FOUT + f]);
    *(short8*)&eyT[(size_t)f * EE + e8 * 8] = pk;
}

// ---------------- K3: out[n][f] += 0.5*D_e[n] * (MT^T @ ey)[n][f] ----------------
// grid (256, 4): 4 blocks/CU. Same reg-double-buffered A (column gather) + LDS B.
__global__ __launch_bounds__(256, 4) void k3_mtT_ey(
    const float* __restrict__ MT, const unsigned short* __restrict__ eyT,
    const float* __restrict__ de, float* __restrict__ out) {
    __shared__ unsigned short blds[2][FOUT * 64];
    const int t  = threadIdx.x;
    const int l  = t & 63;
    const int wv = t >> 6;
    const int q4 = l >> 4;
    const int nBase = blockIdx.x * 64;
    const int sBase = blockIdx.y * 2048;
    const int n = nBase + wv * 16 + (l & 15);

    f32x4 acc[8];
    #pragma unroll
    for (int i = 0; i < 8; ++i) acc[i] = (f32x4)0.0f;

    const int sf = t >> 1;
    const int skoff = (t & 1) * 32;
    const int scb = skoff >> 3;
    const int sfx = sf & 7;
    const unsigned short* srcBase = eyT + (size_t)sf * EE + skoff;

    {   // prologue: stage B chunk 0 into buf 0
        const unsigned short* src = srcBase + sBase;
        short8 v0 = *(const short8*)(src);
        short8 v1 = *(const short8*)(src + 8);
        short8 v2 = *(const short8*)(src + 16);
        short8 v3 = *(const short8*)(src + 24);
        *(short8*)&blds[0][sf * 64 + ((scb + 0) ^ sfx) * 8] = v0;
        *(short8*)&blds[0][sf * 64 + ((scb + 1) ^ sfx) * 8] = v1;
        *(short8*)&blds[0][sf * 64 + ((scb + 2) ^ sfx) * 8] = v2;
        *(short8*)&blds[0][sf * 64 + ((scb + 3) ^ sfx) * 8] = v3;
    }
    short8 aF[2];   // current-chunk A, pre-packed bf16
    {   // prologue: gather + pack A chunk 0
        #pragma unroll
        for (int kk = 0; kk < 2; ++kk) {
            const float* ap = MT + (size_t)(sBase + kk * 32 + q4 * 8) * NN + n;
            float av[8];
            #pragma unroll
            for (int j = 0; j < 8; ++j) av[j] = ap[(size_t)j * NN];
            #pragma unroll
            for (int j = 0; j < 8; ++j) aF[kk][j] = (short)f2bf(av[j]);
        }
    }

    for (int cc = 0; cc < 32; ++cc) {
        __syncthreads();

        // issue next-chunk loads (B staging + A column gather)
        short8 v0, v1, v2, v3;
        float nav[2][8];
        if (cc != 31) {
            const int kn = sBase + cc * 64 + 64;
            const unsigned short* src = srcBase + kn;
            v0 = *(const short8*)(src);
            v1 = *(const short8*)(src + 8);
            v2 = *(const short8*)(src + 16);
            v3 = *(const short8*)(src + 24);
            #pragma unroll
            for (int kk = 0; kk < 2; ++kk) {
                const float* ap = MT + (size_t)(kn + kk * 32 + q4 * 8) * NN + n;
                #pragma unroll
                for (int j = 0; j < 8; ++j) nav[kk][j] = ap[(size_t)j * NN];
            }
        }
        // compute current chunk: pure ds_read_b128 + MFMA
        #pragma unroll
        for (int kk = 0; kk < 2; ++kk) {
            #pragma unroll
            for (int ft = 0; ft < 8; ++ft) {
                int f = ft * 16 + (l & 15);
                int c = (kk * 4 + q4) ^ (f & 7);
                short8 b = *(const short8*)&blds[cc & 1][f * 64 + c * 8];
                acc[ft] = mfma_bf16(aF[kk], b, acc[ft]);
            }
        }
        // commit next chunk
        if (cc != 31) {
            unsigned short* dst = &blds[(cc + 1) & 1][sf * 64];
            *(short8*)&dst[((scb + 0) ^ sfx) * 8] = v0;
            *(short8*)&dst[((scb + 1) ^ sfx) * 8] = v1;
            *(short8*)&dst[((scb + 2) ^ sfx) * 8] = v2;
            *(short8*)&dst[((scb + 3) ^ sfx) * 8] = v3;
            #pragma unroll
            for (int kk = 0; kk < 2; ++kk) {
                #pragma unroll
                for (int j = 0; j < 8; ++j) aF[kk][j] = (short)f2bf(nav[kk][j]);
            }
        }
    }
    // epilogue: scale by 0.5*de[row], then atomic accumulate
    const int no = nBase + wv * 16 + q4 * 4;
    float der[4];
    #pragma unroll
    for (int r = 0; r < 4; ++r) der[r] = 0.5f * de[no + r];
    #pragma unroll
    for (int ft = 0; ft < 8; ++ft) {
        int f = ft * 16 + (l & 15);
        #pragma unroll
        for (int r = 0; r < 4; ++r)
            atomicAdd(&out[(size_t)(no + r) * FOUT + f], der[r] * acc[ft][r]);
    }
}

extern "C" void kernel_launch(void* const* d_in, const int* in_sizes, int n_in,
                              void* d_out, int out_size, void* d_ws, size_t ws_size,
                              hipStream_t stream) {
    const float* x  = (const float*)d_in[0];
    const float* w  = (const float*)d_in[1];
    const float* MT = (const float*)d_in[2];
    const float* dv = (const float*)d_in[3];
    const float* de = (const float*)d_in[4];
    float* out = (float*)d_out;

    char* ws = (char*)d_ws;
    unsigned short* yT  = (unsigned short*)(ws);                 // [128][16384] bf16, 4 MB
    unsigned short* eyT = (unsigned short*)(ws + (4u << 20));    // [128][8192]  bf16, 2 MB
    float*          eyf = (float*)(ws + (6u << 20));             // [8192][128]  f32,  4 MB

    hipMemsetAsync(out, 0, (size_t)NN * FOUT * sizeof(float), stream);
    hipMemsetAsync(eyf, 0, (size_t)EE * FOUT * sizeof(float), stream);

    k1_xw_yT <<<256, 256, 0, stream>>>(x, w, yT);
    k2_mt_y  <<<dim3(128, 8), 256, 0, stream>>>(MT, yT, dv, eyf);
    k2b_cvtT <<<512, 256, 0, stream>>>(eyf, eyT);
    k3_mtT_ey<<<dim3(256, 4), 256, 0, stream>>>(MT, eyT, de, out);
}